// Round 8
// baseline (374.754 us; speedup 1.0000x reference)
//
#include <hip/hip_runtime.h>
#include <hip/hip_fp16.h>
#include <stdint.h>

typedef float f4v __attribute__((ext_vector_type(4)));
typedef _Float16 h8v __attribute__((ext_vector_type(8)));

// ---- workspace byte offsets ----
#define FMT_OFF   0          // f16 fmT [14400][64]                : 1,843,200 B
#define GF_OFF    1843200    // f32 gf[64] channel sums (pre-div)
#define W1P_OFF   1843712    // f16 permuted+swizzled W1 (a,b,c)   : 2,932,736 B
#define W2T_OFF   4776448    // f16 w2t [3][32][128] linear        : 24,576 B
#define PBUF_OFF  4801024    // f16 partials 768 x [128][128]      : 25,165,824 B
// total ~30.0 MB

#define GLD(gp, lp) __builtin_amdgcn_global_load_lds( \
    (const __attribute__((address_space(1))) uint32_t*)(uintptr_t)(gp), \
    (__attribute__((address_space(3))) uint32_t*)(uintptr_t)(lp), 16, 0, 0)

__device__ __forceinline__ unsigned short f2hbits(float f) {
  __half h = __float2half_rn(f);
  union { __half h; unsigned short s; } u; u.h = h; return u.s;
}
__device__ __forceinline__ __half2 uh(unsigned int x) {
  union { unsigned int u; __half2 h; } v; v.u = x; return v.h;
}
__device__ __forceinline__ unsigned int hu(__half2 h) {
  union { __half2 h; unsigned int u; } v; v.h = h; return v.u;
}

// ---- fm [64][120][120] f32 -> fmT [pix][64] f16 (LDS-tiled) + channel sums ----
__global__ void k_transpose(const float* __restrict__ fm, unsigned int* __restrict__ fmT32,
                            float* __restrict__ gf) {
  __shared__ float tile[64][65];
  int pixbase = blockIdx.x * 64, t = threadIdx.x;
  #pragma unroll
  for (int k = 0; k < 16; ++k) {
    int c = k * 4 + (t >> 6);
    tile[c][t & 63] = fm[c * 14400 + pixbase + (t & 63)];
  }
  __syncthreads();
  #pragma unroll
  for (int k = 0; k < 8; ++k) {
    int p = k * 8 + (t >> 5), i = t & 31;
    __half2 h = __floats2half2_rn(tile[2 * i][p], tile[2 * i + 1][p]);
    fmT32[(pixbase + p) * 32 + i] = hu(h);
  }
  int ch = t >> 2, seg = t & 3;
  float s = 0.f;
  #pragma unroll
  for (int j = 0; j < 16; ++j) s += tile[ch][seg * 16 + j];
  s += __shfl_xor(s, 1);
  s += __shfl_xor(s, 2);
  if (seg == 0) atomicAdd(&gf[ch], s);
}

// ---- W1 -> per-point 16KB swizzled f16 chunks; blocks 384..386 do W2 prep ----
__global__ void k_w1w2(const float* __restrict__ W1a, const float* __restrict__ W1b,
                       const float* __restrict__ W1c,
                       const float* __restrict__ W2a, const float* __restrict__ W2b,
                       const float* __restrict__ W2c,
                       unsigned short* __restrict__ w1p, unsigned short* __restrict__ w2t) {
  __shared__ float row[7744];
  int bi = blockIdx.x, t = threadIdx.x;
  if (bi >= 384) {
    int head = bi - 384;
    const float* W2 = head == 0 ? W2a : (head == 1 ? W2b : W2c);
    int od = head == 0 ? 22 : 21;
    #pragma unroll
    for (int it = 0; it < 16; ++it) {
      int e = it * 256 + t;
      int n = e >> 7, k = e & 127;
      float v = (n < od) ? W2[n * 128 + k] : 0.0f;
      w2t[head * 4096 + e] = f2hbits(v);
    }
    return;
  }
  int head = bi >> 7, j = bi & 127;
  const float* W1; int rr, base;
  if (head == 0)      { W1 = W1a; rr = 9;   base = 0; }
  else if (head == 1) { W1 = W1b; rr = 49;  base = 147456; }
  else                { W1 = W1c; rr = 121; base = 950272; }
  int fin = rr * 64;
  for (int idx = t; idx < fin; idx += 256) row[idx] = W1[j * fin + idx];
  __syncthreads();
  int swz = (j & 7) << 4;
  for (int idx = t; idx < fin; idx += 256) {
    int c = idx & 63, p = idx >> 6;
    int byteoff = base + p * 16384 + ((j * 128 + c * 2) ^ swz);
    w1p[byteoff >> 1] = f2hbits(row[c * rr + p]);
  }
}

// ---- bilinear entry: {corner byte-offset, half2(wx,wy)} ----
__device__ __forceinline__ int2 mk_entry(float tx, float ty,
                                         float DX, float BX, float DY, float BY) {
  float ix = tx * DX + BX;
  float iy = ty * DY + BY;
  int x0 = min(max((int)floorf(ix), 0), 118);
  int y0 = min(max((int)floorf(iy), 0), 118);
  float wx = ix - (float)x0;
  float wy = iy - (float)y0;
  return make_int2((y0 * 120 + x0) * 128, (int)hu(__floats2half2_rn(wx, wy)));
}

__device__ __forceinline__ unsigned lerp1(unsigned aa, unsigned bb, unsigned cc, unsigned dd,
                                          __half2 wx2, __half2 wy2) {
  __half2 a = uh(aa), b = uh(bb), c = uh(cc), d = uh(dd);
  __half2 t = __hfma2(wx2, __hsub2(b, a), a);
  __half2 u2 = __hfma2(wx2, __hsub2(d, c), c);
  return hu(__hfma2(wy2, __hsub2(u2, t), t));
}

// issue sample loads for one point: 2 units (boxes sg, sg+64) x 4 corners x 16B
__device__ __forceinline__ void issue_pt(const char* lds, int ebOff, const char* __restrict__ fmT,
                                         int sg, int scg8, uint4 cs[2][4],
                                         __half2* wx2v, __half2* wy2v) {
  #pragma unroll
  for (int u = 0; u < 2; ++u) {
    int2 e = *(const int2*)(lds + ebOff + (sg + u * 64) * 8);
    __half2 wh = uh((unsigned)e.y);
    wx2v[u] = __half2half2(__low2half(wh));
    wy2v[u] = __half2half2(__high2half(wh));
    const char* src = fmT + e.x + scg8 * 16;
    cs[u][0] = *(const uint4*)(src);
    cs[u][1] = *(const uint4*)(src + 128);
    cs[u][2] = *(const uint4*)(src + 15360);
    cs[u][3] = *(const uint4*)(src + 15488);
  }
}

// ---- fused ROI-sample + layer-1 GEMM, 128-box tiles, single-buffer B ----
// LDS: A [0,16K) ; B [16K,32K) ; ebuf[2] [32K, 32K+2K)  => 34,816 B -> 4 blocks/CU
__global__ __launch_bounds__(512, 8) void k_main3(
    const char* __restrict__ fmT,
    const float* __restrict__ boxes,
    const char* __restrict__ w1p,
    unsigned short* __restrict__ pbuf)
{
  __shared__ __align__(16) char lds[34816];
  int bi = blockIdx.x;
  int head, tile, split;
  if (bi < 512)      { head = 2; tile = bi >> 3;  split = bi & 7; }        // 8 splits
  else if (bi < 704) { int b2 = bi - 512; head = 1; tile = b2 / 3; split = b2 - tile * 3; }
  else               { head = 0; tile = bi - 704; split = 0; }

  int psta, pcnt, w1base, R, rm; float invd;
  if (head == 2)      { psta = split ? 15 * split + 1 : 0; pcnt = split ? 15 : 16;
                        w1base = 950272; R = 11; rm = 5958;  invd = 0.1f; }
  else if (head == 1) { psta = split ? 16 * split + 1 : 0; pcnt = split ? 16 : 17;
                        w1base = 147456; R = 7;  rm = 9363;  invd = 0.166666667f; }
  else                { psta = 0; pcnt = 9; w1base = 0; R = 3; rm = 21846; invd = 0.5f; }

  int tid = threadIdx.x;
  int w = tid >> 6, lane = tid & 63;
  int l15 = lane & 15, kgrp = lane >> 4;
  int wm = w & 1, wc = w >> 1;          // wave tile: 64 boxes x 32 cols
  int sg = tid >> 3, scg8 = tid & 7;    // sampler: boxes sg, sg+64; 8-ch group
  int boxbase = tile * 128;

  // box params for entry compute (tid<128 owns box=tid)
  float DX = 0.f, BX = 0.f, DY = 0.f, BY = 0.f;
  if (tid < 128) {
    float4 bx = ((const float4*)boxes)[boxbase + tid];
    const float sc2 = 119.0f / 960.0f;
    DX = (bx.z - bx.x) * sc2; BX = bx.x * sc2;
    DY = (bx.w - bx.y) * sc2; BY = bx.y * sc2;
  }

  f4v acc[4][2];
  #pragma unroll
  for (int m = 0; m < 4; ++m)
    #pragma unroll
    for (int n = 0; n < 2; ++n) acc[m][n] = (f4v){0.f, 0.f, 0.f, 0.f};

  const char* w1g = w1p + w1base;
  uint4 cs[2][4];
  __half2 wx2v[2], wy2v[2];

  // ---- prologue: entries(0)->ebuf[0], entries(1)->ebuf[1]; GLD B(0) ----
  if (tid < 128) {
    #pragma unroll
    for (int q = 0; q < 2; ++q) {
      int p = psta + q;
      int py = (p * rm) >> 16, px = p - py * R;
      *(int2*)(lds + 32768 + q * 1024 + tid * 8) =
          mk_entry((float)px * invd, (float)py * invd, DX, BX, DY, BY);
    }
  }
  {
    const char* s0 = w1g + psta * 16384 + w * 2048 + lane * 16;
    char* d0 = lds + 16384 + w * 2048;
    GLD(s0, d0); GLD(s0 + 1024, d0 + 1024);
  }
  __syncthreads();
  issue_pt(lds, 32768, fmT, sg, scg8, cs, wx2v, wy2v);   // corners(0)

  for (int t = 0; t < pcnt; ++t) {
    int cur = t & 1, nxt = cur ^ 1;

    // ---- phase A: GLD B(t) (t>0; B(t-1) readers done at bar2), lerp(t)->A, entries(t+2) ----
    if (t > 0) {
      const char* s0 = w1g + (psta + t) * 16384 + w * 2048 + lane * 16;
      char* d0 = lds + 16384 + w * 2048;
      GLD(s0, d0); GLD(s0 + 1024, d0 + 1024);
    }
    #pragma unroll
    for (int u = 0; u < 2; ++u) {
      int sbox = sg + u * 64;
      uint4 r;
      r.x = lerp1(cs[u][0].x, cs[u][1].x, cs[u][2].x, cs[u][3].x, wx2v[u], wy2v[u]);
      r.y = lerp1(cs[u][0].y, cs[u][1].y, cs[u][2].y, cs[u][3].y, wx2v[u], wy2v[u]);
      r.z = lerp1(cs[u][0].z, cs[u][1].z, cs[u][2].z, cs[u][3].z, wx2v[u], wy2v[u]);
      r.w = lerp1(cs[u][0].w, cs[u][1].w, cs[u][2].w, cs[u][3].w, wx2v[u], wy2v[u]);
      *(uint4*)(lds + ((sbox * 128 + scg8 * 16) ^ ((sbox & 7) << 4))) = r;
    }
    int2 ne;
    if (tid < 128) {
      int p = psta + min(t + 2, pcnt - 1);
      int py = (p * rm) >> 16, px = p - py * R;
      ne = mk_entry((float)px * invd, (float)py * invd, DX, BX, DY, BY);
    }
    __syncthreads();   // bar1: A(t) visible; GLD B(t) drained (vmcnt0 before barrier)

    // ---- phase B: entries ds_write, issue corners(t+1), MFMA(t) ----
    if (tid < 128) *(int2*)(lds + 32768 + cur * 1024 + tid * 8) = ne;
    if (t + 1 < pcnt)
      issue_pt(lds, 32768 + nxt * 1024, fmT, sg, scg8, cs, wx2v, wy2v);
    {
      const char* bb = lds + 16384;
      #pragma unroll
      for (int ks = 0; ks < 2; ++ks) {
        int n0 = wc * 32 + l15, n1 = n0 + 16;
        h8v bf0 = *(const h8v*)(bb + ((n0 * 128 + ks * 64 + kgrp * 16) ^ ((n0 & 7) << 4)));
        h8v bf1 = *(const h8v*)(bb + ((n1 * 128 + ks * 64 + kgrp * 16) ^ ((n1 & 7) << 4)));
        #pragma unroll
        for (int m = 0; m < 4; ++m) {
          int rrow = wm * 64 + m * 16 + l15;
          h8v af = *(const h8v*)(lds + ((rrow * 128 + ks * 64 + kgrp * 16) ^ ((rrow & 7) << 4)));
          acc[m][0] = __builtin_amdgcn_mfma_f32_16x16x32_f16(af, bf0, acc[m][0], 0, 0, 0);
          acc[m][1] = __builtin_amdgcn_mfma_f32_16x16x32_f16(af, bf1, acc[m][1], 0, 0, 0);
        }
      }
    }
    __syncthreads();   // bar2: B(t)/A(t) readers done; next iter may overwrite
  }

  // ---- epilogue: f16 partial -> pbuf[bi] ----
  unsigned short* pdst = pbuf + (size_t)bi * 16384;
  #pragma unroll
  for (int m = 0; m < 4; ++m)
    #pragma unroll
    for (int n = 0; n < 2; ++n)
      #pragma unroll
      for (int e = 0; e < 4; ++e) {
        int boxl = wm * 64 + m * 16 + kgrp * 4 + e;
        int cnl = wc * 32 + n * 16 + l15;
        pdst[boxl * 128 + cnl] = f2hbits(acc[m][n][e]);
      }
}

// ---- combine partials, bias+relu, layer-2 MFMA, write out (+g cols) ----
__global__ __launch_bounds__(256) void k_combine(
    const unsigned short* __restrict__ pbuf,
    const unsigned short* __restrict__ w2t,
    const float* __restrict__ gf,
    const float* __restrict__ Wg, const float* __restrict__ bg,
    const float* __restrict__ b1a, const float* __restrict__ b1b, const float* __restrict__ b1c,
    const float* __restrict__ b2a, const float* __restrict__ b2b, const float* __restrict__ b2c,
    const float* __restrict__ scale_w,
    float* __restrict__ out)
{
  __shared__ __align__(16) char lds[8192 + 256];
  float* gv = (float*)(lds + 8192);
  int b = blockIdx.x, tid = threadIdx.x;
  int tile = b >> 2, rowoff = (b & 3) * 32;
  int boxbase = b * 32;
  int w = tid >> 6, lane = tid & 63, l15 = lane & 15, kgrp = lane >> 4;

  if (tid < 16) {
    float s = bg[tid];
    for (int c = 0; c < 64; ++c) s += gf[c] * (1.0f / 14400.0f) * Wg[tid * 64 + c];
    gv[tid] = s;
  }

  int row = tid >> 3, col0 = (tid & 7) * 16;
  const float* b1s[3] = {b1a, b1b, b1c};
  const float* b2s[3] = {b2a, b2b, b2c};

  #pragma unroll
  for (int h = 0; h < 3; ++h) {
    int S, pb, colbase, odh;
    if (h == 0)      { S = 1; pb = 704 + tile;     colbase = 0;  odh = 22; }
    else if (h == 1) { S = 3; pb = 512 + tile * 3; colbase = 22; odh = 21; }
    else             { S = 8; pb = tile * 8;       colbase = 43; odh = 5; }

    float f[16];
    #pragma unroll
    for (int j = 0; j < 16; ++j) f[j] = 0.f;
    #pragma unroll
    for (int s = 0; s < 8; ++s) {
      if (s < S) {
        const unsigned short* src = pbuf + (size_t)(pb + s) * 16384 + (rowoff + row) * 128 + col0;
        uint4 v0 = *(const uint4*)(src);
        uint4 v1 = *(const uint4*)(src + 8);
        unsigned int uu[8] = {v0.x, v0.y, v0.z, v0.w, v1.x, v1.y, v1.z, v1.w};
        #pragma unroll
        for (int k = 0; k < 8; ++k) {
          __half2 hv = uh(uu[k]);
          f[k * 2]     += __low2float(hv);
          f[k * 2 + 1] += __high2float(hv);
        }
      }
    }
    unsigned int pk[8];
    #pragma unroll
    for (int k = 0; k < 8; ++k) {
      float a  = fmaxf(f[2 * k]     + b1s[h][col0 + 2 * k],     0.f);
      float c2 = fmaxf(f[2 * k + 1] + b1s[h][col0 + 2 * k + 1], 0.f);
      pk[k] = hu(__floats2half2_rn(a, c2));
    }
    int swz = (row & 15) << 4;
    int a0 = (row * 256 + col0 * 2) ^ swz;
    int a1 = (row * 256 + col0 * 2 + 16) ^ swz;
    *(uint4*)(lds + a0) = make_uint4(pk[0], pk[1], pk[2], pk[3]);
    *(uint4*)(lds + a1) = make_uint4(pk[4], pk[5], pk[6], pk[7]);
    __syncthreads();

    {
      int m = w & 1, n2 = w >> 1;
      f4v a2 = (f4v){0.f, 0.f, 0.f, 0.f};
      int hrow = m * 16 + l15, drow = n2 * 16 + l15;
      #pragma unroll
      for (int ks = 0; ks < 4; ++ks) {
        h8v ha = *(const h8v*)(lds + ((hrow * 256 + ks * 64 + kgrp * 16) ^ ((hrow & 15) << 4)));
        h8v wb = *(const h8v*)((const char*)w2t + h * 8192 + drow * 256 + ks * 64 + kgrp * 16);
        a2 = __builtin_amdgcn_mfma_f32_16x16x32_f16(ha, wb, a2, 0, 0, 0);
      }
      if (drow < odh) {
        float scv = scale_w[h];
        float b2v = b2s[h][drow];
        #pragma unroll
        for (int e = 0; e < 4; ++e) {
          int box = boxbase + m * 16 + kgrp * 4 + e;
          out[box * 64 + colbase + drow] = fmaxf(a2[e] + b2v, 0.f) * scv;
        }
      }
    }
    __syncthreads();
  }

  {
    int i0 = tid * 2;
    #pragma unroll
    for (int j2 = 0; j2 < 2; ++j2) {
      int idx = i0 + j2;
      out[(boxbase + (idx >> 4)) * 64 + 48 + (idx & 15)] = gv[idx & 15];
    }
  }
}

extern "C" void kernel_launch(void* const* d_in, const int* in_sizes, int n_in,
                              void* d_out, int out_size, void* d_ws, size_t ws_size,
                              hipStream_t stream) {
  const float* fm      = (const float*)d_in[0];
  const float* boxes   = (const float*)d_in[1];
  const float* W1a     = (const float*)d_in[2];
  const float* b1a     = (const float*)d_in[3];
  const float* W2a     = (const float*)d_in[4];
  const float* b2a     = (const float*)d_in[5];
  const float* W1b     = (const float*)d_in[6];
  const float* b1b     = (const float*)d_in[7];
  const float* W2b     = (const float*)d_in[8];
  const float* b2b     = (const float*)d_in[9];
  const float* W1c     = (const float*)d_in[10];
  const float* b1c     = (const float*)d_in[11];
  const float* W2c     = (const float*)d_in[12];
  const float* b2c     = (const float*)d_in[13];
  const float* scale_w = (const float*)d_in[14];
  const float* Wg      = (const float*)d_in[15];
  const float* bg      = (const float*)d_in[16];

  char* ws = (char*)d_ws;
  unsigned int* fmT32 = (unsigned int*)(ws + FMT_OFF);
  float* gf           = (float*)(ws + GF_OFF);
  unsigned short* w1p = (unsigned short*)(ws + W1P_OFF);
  unsigned short* w2t = (unsigned short*)(ws + W2T_OFF);
  unsigned short* pbuf= (unsigned short*)(ws + PBUF_OFF);
  float* out          = (float*)d_out;

  hipMemsetAsync(gf, 0, 256, stream);
  k_transpose<<<225, 256, 0, stream>>>(fm, fmT32, gf);
  k_w1w2<<<387, 256, 0, stream>>>(W1a, W1b, W1c, W2a, W2b, W2c, w1p, w2t);
  k_main3<<<768, 512, 0, stream>>>((const char*)ws + FMT_OFF, boxes,
                                   (const char*)ws + W1P_OFF, pbuf);
  k_combine<<<256, 256, 0, stream>>>(pbuf, w2t, gf, Wg, bg,
                                     b1a, b1b, b1c, b2a, b2b, b2c, scale_w, out);
}

// Round 9
// 214.081 us; speedup vs baseline: 1.7505x; 1.7505x over previous
//
#include <hip/hip_runtime.h>
#include <hip/hip_fp16.h>
#include <stdint.h>

typedef float f4v __attribute__((ext_vector_type(4)));
typedef _Float16 h8v __attribute__((ext_vector_type(8)));

// ---- workspace byte offsets ----
#define FMT_OFF   0          // f16 fmT [14400][64]                : 1,843,200 B
#define GF_OFF    1843200    // f32 gf[64] channel sums (pre-div)
#define W1P_OFF   1843712    // f16 permuted+swizzled W1 (a,b,c)   : 2,932,736 B
#define W2T_OFF   4776448    // f16 w2t [3][32][128] linear        : 24,576 B
#define PBUF_OFF  4801024    // f16 partials 768 x [128][128]      : 25,165,824 B
// total ~30.0 MB

#define GLD(gp, lp) __builtin_amdgcn_global_load_lds( \
    (const __attribute__((address_space(1))) uint32_t*)(uintptr_t)(gp), \
    (__attribute__((address_space(3))) uint32_t*)(uintptr_t)(lp), 16, 0, 0)

__device__ __forceinline__ unsigned short f2hbits(float f) {
  __half h = __float2half_rn(f);
  union { __half h; unsigned short s; } u; u.h = h; return u.s;
}
__device__ __forceinline__ __half2 uh(unsigned int x) {
  union { unsigned int u; __half2 h; } v; v.u = x; return v.h;
}
__device__ __forceinline__ unsigned int hu(__half2 h) {
  union { __half2 h; unsigned int u; } v; v.h = h; return v.u;
}

// ---- fm [64][120][120] f32 -> fmT [pix][64] f16 (LDS-tiled) + channel sums ----
__global__ void k_transpose(const float* __restrict__ fm, unsigned int* __restrict__ fmT32,
                            float* __restrict__ gf) {
  __shared__ float tile[64][65];
  int pixbase = blockIdx.x * 64, t = threadIdx.x;
  #pragma unroll
  for (int k = 0; k < 16; ++k) {
    int c = k * 4 + (t >> 6);
    tile[c][t & 63] = fm[c * 14400 + pixbase + (t & 63)];
  }
  __syncthreads();
  #pragma unroll
  for (int k = 0; k < 8; ++k) {
    int p = k * 8 + (t >> 5), i = t & 31;
    __half2 h = __floats2half2_rn(tile[2 * i][p], tile[2 * i + 1][p]);
    fmT32[(pixbase + p) * 32 + i] = hu(h);
  }
  int ch = t >> 2, seg = t & 3;
  float s = 0.f;
  #pragma unroll
  for (int j = 0; j < 16; ++j) s += tile[ch][seg * 16 + j];
  s += __shfl_xor(s, 1);
  s += __shfl_xor(s, 2);
  if (seg == 0) atomicAdd(&gf[ch], s);
}

// ---- W1 -> per-point 16KB swizzled f16 chunks; blocks 384..386 do W2 prep ----
__global__ void k_w1w2(const float* __restrict__ W1a, const float* __restrict__ W1b,
                       const float* __restrict__ W1c,
                       const float* __restrict__ W2a, const float* __restrict__ W2b,
                       const float* __restrict__ W2c,
                       unsigned short* __restrict__ w1p, unsigned short* __restrict__ w2t) {
  __shared__ float row[7744];
  int bi = blockIdx.x, t = threadIdx.x;
  if (bi >= 384) {
    int head = bi - 384;
    const float* W2 = head == 0 ? W2a : (head == 1 ? W2b : W2c);
    int od = head == 0 ? 22 : 21;
    #pragma unroll
    for (int it = 0; it < 16; ++it) {
      int e = it * 256 + t;
      int n = e >> 7, k = e & 127;
      float v = (n < od) ? W2[n * 128 + k] : 0.0f;
      w2t[head * 4096 + e] = f2hbits(v);
    }
    return;
  }
  int head = bi >> 7, j = bi & 127;
  const float* W1; int rr, base;
  if (head == 0)      { W1 = W1a; rr = 9;   base = 0; }
  else if (head == 1) { W1 = W1b; rr = 49;  base = 147456; }
  else                { W1 = W1c; rr = 121; base = 950272; }
  int fin = rr * 64;
  for (int idx = t; idx < fin; idx += 256) row[idx] = W1[j * fin + idx];
  __syncthreads();
  int swz = (j & 7) << 4;
  for (int idx = t; idx < fin; idx += 256) {
    int c = idx & 63, p = idx >> 6;
    int byteoff = base + p * 16384 + ((j * 128 + c * 2) ^ swz);
    w1p[byteoff >> 1] = f2hbits(row[c * rr + p]);
  }
}

// ---- bilinear entry: {corner byte-offset, half2(wx,wy)} ----
__device__ __forceinline__ int2 mk_entry(float tx, float ty,
                                         float DX, float BX, float DY, float BY) {
  float ix = tx * DX + BX;
  float iy = ty * DY + BY;
  int x0 = min(max((int)floorf(ix), 0), 118);
  int y0 = min(max((int)floorf(iy), 0), 118);
  float wx = ix - (float)x0;
  float wy = iy - (float)y0;
  return make_int2((y0 * 120 + x0) * 128, (int)hu(__floats2half2_rn(wx, wy)));
}

__device__ __forceinline__ unsigned lerp1(unsigned aa, unsigned bb, unsigned cc, unsigned dd,
                                          __half2 wx2, __half2 wy2) {
  __half2 a = uh(aa), b = uh(bb), c = uh(cc), d = uh(dd);
  __half2 t = __hfma2(wx2, __hsub2(b, a), a);
  __half2 u2 = __hfma2(wx2, __hsub2(d, c), c);
  return hu(__hfma2(wy2, __hsub2(u2, t), t));
}

// issue 4 corner loads (16B each) for one (box-unit u, 8-ch group)
__device__ __forceinline__ void issue_unit(const char* lds, int ebOff,
                                           const char* __restrict__ fmT,
                                           int sg, int scg8, int u, uint4 cs[4],
                                           __half2& wx2, __half2& wy2) {
  int2 e = *(const int2*)(lds + ebOff + (sg + u * 64) * 8);
  __half2 wh = uh((unsigned)e.y);
  wx2 = __half2half2(__low2half(wh));
  wy2 = __half2half2(__high2half(wh));
  const char* src = fmT + e.x + scg8 * 16;
  cs[0] = *(const uint4*)(src);
  cs[1] = *(const uint4*)(src + 128);
  cs[2] = *(const uint4*)(src + 15360);
  cs[3] = *(const uint4*)(src + 15488);
}

__device__ __forceinline__ void lerp_store(char* lds, int sg, int scg8, int u,
                                           const uint4 cs[4], __half2 wx2, __half2 wy2) {
  int sbox = sg + u * 64;
  uint4 r;
  r.x = lerp1(cs[0].x, cs[1].x, cs[2].x, cs[3].x, wx2, wy2);
  r.y = lerp1(cs[0].y, cs[1].y, cs[2].y, cs[3].y, wx2, wy2);
  r.z = lerp1(cs[0].z, cs[1].z, cs[2].z, cs[3].z, wx2, wy2);
  r.w = lerp1(cs[0].w, cs[1].w, cs[2].w, cs[3].w, wx2, wy2);
  *(uint4*)(lds + ((sbox * 128 + scg8 * 16) ^ ((sbox & 7) << 4))) = r;
}

// ---- fused ROI-sample + layer-1 GEMM, 128-box tiles, single-buffer B ----
// LDS: A [0,16K) ; B [16K,32K) ; ebuf[2] [32K, 32K+2K)  => 34,816 B
// __launch_bounds__(512,6): 85-reg cap -> 3 blocks/CU, no spill (peak live ~75)
__global__ __launch_bounds__(512, 6) void k_main3(
    const char* __restrict__ fmT,
    const float* __restrict__ boxes,
    const char* __restrict__ w1p,
    unsigned short* __restrict__ pbuf)
{
  __shared__ __align__(16) char lds[34816];
  int bi = blockIdx.x;
  int head, tile, split;
  if (bi < 512)      { head = 2; tile = bi >> 3;  split = bi & 7; }        // 8 splits
  else if (bi < 704) { int b2 = bi - 512; head = 1; tile = b2 / 3; split = b2 - tile * 3; }
  else               { head = 0; tile = bi - 704; split = 0; }

  int psta, pcnt, w1base, R, rm; float invd;
  if (head == 2)      { psta = split ? 15 * split + 1 : 0; pcnt = split ? 15 : 16;
                        w1base = 950272; R = 11; rm = 5958;  invd = 0.1f; }
  else if (head == 1) { psta = split ? 16 * split + 1 : 0; pcnt = split ? 16 : 17;
                        w1base = 147456; R = 7;  rm = 9363;  invd = 0.166666667f; }
  else                { psta = 0; pcnt = 9; w1base = 0; R = 3; rm = 21846; invd = 0.5f; }

  int tid = threadIdx.x;
  int w = tid >> 6, lane = tid & 63;
  int l15 = lane & 15, kgrp = lane >> 4;
  int wm = w & 1, wc = w >> 1;          // wave tile: 64 boxes x 32 cols
  int sg = tid >> 3, scg8 = tid & 7;    // sampler: boxes sg, sg+64; 8-ch group
  int boxbase = tile * 128;

  // box params for entry compute (tid<128 owns box=tid)
  float DX = 0.f, BX = 0.f, DY = 0.f, BY = 0.f;
  if (tid < 128) {
    float4 bx = ((const float4*)boxes)[boxbase + tid];
    const float sc2 = 119.0f / 960.0f;
    DX = (bx.z - bx.x) * sc2; BX = bx.x * sc2;
    DY = (bx.w - bx.y) * sc2; BY = bx.y * sc2;
  }

  f4v acc[4][2];
  #pragma unroll
  for (int m = 0; m < 4; ++m)
    #pragma unroll
    for (int n = 0; n < 2; ++n) acc[m][n] = (f4v){0.f, 0.f, 0.f, 0.f};

  const char* w1g = w1p + w1base;
  uint4 cs0[4], cs1[4];
  __half2 wx0, wy0, wx1, wy1;

  // ---- prologue: entries(0)->ebuf[0], entries(1)->ebuf[1]; GLD B(0) ----
  if (tid < 128) {
    #pragma unroll
    for (int q = 0; q < 2; ++q) {
      int p = psta + q;
      int py = (p * rm) >> 16, px = p - py * R;
      *(int2*)(lds + 32768 + q * 1024 + tid * 8) =
          mk_entry((float)px * invd, (float)py * invd, DX, BX, DY, BY);
    }
  }
  {
    const char* s0 = w1g + psta * 16384 + w * 2048 + lane * 16;
    char* d0 = lds + 16384 + w * 2048;
    GLD(s0, d0); GLD(s0 + 1024, d0 + 1024);
  }
  __syncthreads();
  issue_unit(lds, 32768, fmT, sg, scg8, 0, cs0, wx0, wy0);   // pt0 unit0

  for (int t = 0; t < pcnt; ++t) {
    int cur = t & 1, nxt = cur ^ 1;

    // ---- phase A: GLD B(t) (t>0), lerp u0, issue u1, entries(t+2), lerp u1 ----
    if (t > 0) {
      const char* s0 = w1g + (psta + t) * 16384 + w * 2048 + lane * 16;
      char* d0 = lds + 16384 + w * 2048;
      GLD(s0, d0); GLD(s0 + 1024, d0 + 1024);
    }
    lerp_store(lds, sg, scg8, 0, cs0, wx0, wy0);
    issue_unit(lds, 32768 + cur * 1024, fmT, sg, scg8, 1, cs1, wx1, wy1);
    int2 ne;
    if (tid < 128) {
      int p = psta + min(t + 2, pcnt - 1);
      int py = (p * rm) >> 16, px = p - py * R;
      ne = mk_entry((float)px * invd, (float)py * invd, DX, BX, DY, BY);
    }
    lerp_store(lds, sg, scg8, 1, cs1, wx1, wy1);
    __syncthreads();   // bar1: A(t) visible; GLD B(t) drained

    // ---- phase B: entries ds_write, issue u0(t+1), MFMA(t) ----
    if (tid < 128) *(int2*)(lds + 32768 + cur * 1024 + tid * 8) = ne;
    if (t + 1 < pcnt)
      issue_unit(lds, 32768 + nxt * 1024, fmT, sg, scg8, 0, cs0, wx0, wy0);
    {
      const char* bb = lds + 16384;
      #pragma unroll
      for (int ks = 0; ks < 2; ++ks) {
        int n0 = wc * 32 + l15, n1 = n0 + 16;
        h8v bf0 = *(const h8v*)(bb + ((n0 * 128 + ks * 64 + kgrp * 16) ^ ((n0 & 7) << 4)));
        h8v bf1 = *(const h8v*)(bb + ((n1 * 128 + ks * 64 + kgrp * 16) ^ ((n1 & 7) << 4)));
        #pragma unroll
        for (int m = 0; m < 4; ++m) {
          int rrow = wm * 64 + m * 16 + l15;
          h8v af = *(const h8v*)(lds + ((rrow * 128 + ks * 64 + kgrp * 16) ^ ((rrow & 7) << 4)));
          acc[m][0] = __builtin_amdgcn_mfma_f32_16x16x32_f16(af, bf0, acc[m][0], 0, 0, 0);
          acc[m][1] = __builtin_amdgcn_mfma_f32_16x16x32_f16(af, bf1, acc[m][1], 0, 0, 0);
        }
      }
    }
    __syncthreads();   // bar2: B(t)/A(t) readers done; next iter may overwrite
  }

  // ---- epilogue: f16 partial -> pbuf[bi] ----
  unsigned short* pdst = pbuf + (size_t)bi * 16384;
  #pragma unroll
  for (int m = 0; m < 4; ++m)
    #pragma unroll
    for (int n = 0; n < 2; ++n)
      #pragma unroll
      for (int e = 0; e < 4; ++e) {
        int boxl = wm * 64 + m * 16 + kgrp * 4 + e;
        int cnl = wc * 32 + n * 16 + l15;
        pdst[boxl * 128 + cnl] = f2hbits(acc[m][n][e]);
      }
}

// ---- combine partials, bias+relu, layer-2 MFMA, write out (+g cols) ----
__global__ __launch_bounds__(256) void k_combine(
    const unsigned short* __restrict__ pbuf,
    const unsigned short* __restrict__ w2t,
    const float* __restrict__ gf,
    const float* __restrict__ Wg, const float* __restrict__ bg,
    const float* __restrict__ b1a, const float* __restrict__ b1b, const float* __restrict__ b1c,
    const float* __restrict__ b2a, const float* __restrict__ b2b, const float* __restrict__ b2c,
    const float* __restrict__ scale_w,
    float* __restrict__ out)
{
  __shared__ __align__(16) char lds[8192 + 256];
  float* gv = (float*)(lds + 8192);
  int b = blockIdx.x, tid = threadIdx.x;
  int tile = b >> 2, rowoff = (b & 3) * 32;
  int boxbase = b * 32;
  int w = tid >> 6, lane = tid & 63, l15 = lane & 15, kgrp = lane >> 4;

  if (tid < 16) {
    float s = bg[tid];
    for (int c = 0; c < 64; ++c) s += gf[c] * (1.0f / 14400.0f) * Wg[tid * 64 + c];
    gv[tid] = s;
  }

  int row = tid >> 3, col0 = (tid & 7) * 16;
  const float* b1s[3] = {b1a, b1b, b1c};
  const float* b2s[3] = {b2a, b2b, b2c};

  #pragma unroll
  for (int h = 0; h < 3; ++h) {
    int S, pb, colbase, odh;
    if (h == 0)      { S = 1; pb = 704 + tile;     colbase = 0;  odh = 22; }
    else if (h == 1) { S = 3; pb = 512 + tile * 3; colbase = 22; odh = 21; }
    else             { S = 8; pb = tile * 8;       colbase = 43; odh = 5; }

    float f[16];
    #pragma unroll
    for (int j = 0; j < 16; ++j) f[j] = 0.f;
    #pragma unroll
    for (int s = 0; s < 8; ++s) {
      if (s < S) {
        const unsigned short* src = pbuf + (size_t)(pb + s) * 16384 + (rowoff + row) * 128 + col0;
        uint4 v0 = *(const uint4*)(src);
        uint4 v1 = *(const uint4*)(src + 8);
        unsigned int uu[8] = {v0.x, v0.y, v0.z, v0.w, v1.x, v1.y, v1.z, v1.w};
        #pragma unroll
        for (int k = 0; k < 8; ++k) {
          __half2 hv = uh(uu[k]);
          f[k * 2]     += __low2float(hv);
          f[k * 2 + 1] += __high2float(hv);
        }
      }
    }
    unsigned int pk[8];
    #pragma unroll
    for (int k = 0; k < 8; ++k) {
      float a  = fmaxf(f[2 * k]     + b1s[h][col0 + 2 * k],     0.f);
      float c2 = fmaxf(f[2 * k + 1] + b1s[h][col0 + 2 * k + 1], 0.f);
      pk[k] = hu(__floats2half2_rn(a, c2));
    }
    int swz = (row & 15) << 4;
    int a0 = (row * 256 + col0 * 2) ^ swz;
    int a1 = (row * 256 + col0 * 2 + 16) ^ swz;
    *(uint4*)(lds + a0) = make_uint4(pk[0], pk[1], pk[2], pk[3]);
    *(uint4*)(lds + a1) = make_uint4(pk[4], pk[5], pk[6], pk[7]);
    __syncthreads();

    {
      int m = w & 1, n2 = w >> 1;
      f4v a2 = (f4v){0.f, 0.f, 0.f, 0.f};
      int hrow = m * 16 + l15, drow = n2 * 16 + l15;
      #pragma unroll
      for (int ks = 0; ks < 4; ++ks) {
        h8v ha = *(const h8v*)(lds + ((hrow * 256 + ks * 64 + kgrp * 16) ^ ((hrow & 15) << 4)));
        h8v wb = *(const h8v*)((const char*)w2t + h * 8192 + drow * 256 + ks * 64 + kgrp * 16);
        a2 = __builtin_amdgcn_mfma_f32_16x16x32_f16(ha, wb, a2, 0, 0, 0);
      }
      if (drow < odh) {
        float scv = scale_w[h];
        float b2v = b2s[h][drow];
        #pragma unroll
        for (int e = 0; e < 4; ++e) {
          int box = boxbase + m * 16 + kgrp * 4 + e;
          out[box * 64 + colbase + drow] = fmaxf(a2[e] + b2v, 0.f) * scv;
        }
      }
    }
    __syncthreads();
  }

  {
    int i0 = tid * 2;
    #pragma unroll
    for (int j2 = 0; j2 < 2; ++j2) {
      int idx = i0 + j2;
      out[(boxbase + (idx >> 4)) * 64 + 48 + (idx & 15)] = gv[idx & 15];
    }
  }
}

extern "C" void kernel_launch(void* const* d_in, const int* in_sizes, int n_in,
                              void* d_out, int out_size, void* d_ws, size_t ws_size,
                              hipStream_t stream) {
  const float* fm      = (const float*)d_in[0];
  const float* boxes   = (const float*)d_in[1];
  const float* W1a     = (const float*)d_in[2];
  const float* b1a     = (const float*)d_in[3];
  const float* W2a     = (const float*)d_in[4];
  const float* b2a     = (const float*)d_in[5];
  const float* W1b     = (const float*)d_in[6];
  const float* b1b     = (const float*)d_in[7];
  const float* W2b     = (const float*)d_in[8];
  const float* b2b     = (const float*)d_in[9];
  const float* W1c     = (const float*)d_in[10];
  const float* b1c     = (const float*)d_in[11];
  const float* W2c     = (const float*)d_in[12];
  const float* b2c     = (const float*)d_in[13];
  const float* scale_w = (const float*)d_in[14];
  const float* Wg      = (const float*)d_in[15];
  const float* bg      = (const float*)d_in[16];

  char* ws = (char*)d_ws;
  unsigned int* fmT32 = (unsigned int*)(ws + FMT_OFF);
  float* gf           = (float*)(ws + GF_OFF);
  unsigned short* w1p = (unsigned short*)(ws + W1P_OFF);
  unsigned short* w2t = (unsigned short*)(ws + W2T_OFF);
  unsigned short* pbuf= (unsigned short*)(ws + PBUF_OFF);
  float* out          = (float*)d_out;

  hipMemsetAsync(gf, 0, 256, stream);
  k_transpose<<<225, 256, 0, stream>>>(fm, fmT32, gf);
  k_w1w2<<<387, 256, 0, stream>>>(W1a, W1b, W1c, W2a, W2b, W2c, w1p, w2t);
  k_main3<<<768, 512, 0, stream>>>((const char*)ws + FMT_OFF, boxes,
                                   (const char*)ws + W1P_OFF, pbuf);
  k_combine<<<256, 256, 0, stream>>>(pbuf, w2t, gf, Wg, bg,
                                     b1a, b1b, b1c, b2a, b2b, b2c, scale_w, out);
}

// Round 11
// 168.742 us; speedup vs baseline: 2.2209x; 1.2687x over previous
//
#include <hip/hip_runtime.h>
#include <hip/hip_fp16.h>
#include <stdint.h>

typedef float f4v __attribute__((ext_vector_type(4)));
typedef _Float16 h8v __attribute__((ext_vector_type(8)));

// ---- workspace byte offsets ----
#define FMT_OFF   0          // f16 fmT [14400][64]                : 1,843,200 B
#define GF_OFF    1843200    // f32 gf[64] channel sums (pre-div)
#define W1P_OFF   1843712    // f16 permuted+swizzled W1 (a,b,c)   : 2,932,736 B
#define W2T_OFF   4776448    // f16 w2t [3][32][128] linear        : 24,576 B
#define PBUF_OFF  4801024    // f16 partials 768 x [128][128]      : 25,165,824 B
// total ~30.0 MB

#define GLD(gp, lp) __builtin_amdgcn_global_load_lds( \
    (const __attribute__((address_space(1))) uint32_t*)(uintptr_t)(gp), \
    (__attribute__((address_space(3))) uint32_t*)(uintptr_t)(lp), 16, 0, 0)

__device__ __forceinline__ unsigned short f2hbits(float f) {
  __half h = __float2half_rn(f);
  union { __half h; unsigned short s; } u; u.h = h; return u.s;
}
__device__ __forceinline__ __half2 uh(unsigned int x) {
  union { unsigned int u; __half2 h; } v; v.u = x; return v.h;
}
__device__ __forceinline__ unsigned int hu(__half2 h) {
  union { __half2 h; unsigned int u; } v; v.h = h; return v.u;
}

// ---- fm [64][120][120] f32 -> fmT [pix][64] f16 (LDS-tiled) + channel sums ----
__global__ void k_transpose(const float* __restrict__ fm, unsigned int* __restrict__ fmT32,
                            float* __restrict__ gf) {
  __shared__ float tile[64][65];
  int pixbase = blockIdx.x * 64, t = threadIdx.x;
  #pragma unroll
  for (int k = 0; k < 16; ++k) {
    int c = k * 4 + (t >> 6);
    tile[c][t & 63] = fm[c * 14400 + pixbase + (t & 63)];
  }
  __syncthreads();
  #pragma unroll
  for (int k = 0; k < 8; ++k) {
    int p = k * 8 + (t >> 5), i = t & 31;
    __half2 h = __floats2half2_rn(tile[2 * i][p], tile[2 * i + 1][p]);
    fmT32[(pixbase + p) * 32 + i] = hu(h);
  }
  int ch = t >> 2, seg = t & 3;
  float s = 0.f;
  #pragma unroll
  for (int j = 0; j < 16; ++j) s += tile[ch][seg * 16 + j];
  s += __shfl_xor(s, 1);
  s += __shfl_xor(s, 2);
  if (seg == 0) atomicAdd(&gf[ch], s);
}

// ---- W1 -> per-point 16KB swizzled f16 chunks; blocks 384..386 do W2 prep ----
__global__ void k_w1w2(const float* __restrict__ W1a, const float* __restrict__ W1b,
                       const float* __restrict__ W1c,
                       const float* __restrict__ W2a, const float* __restrict__ W2b,
                       const float* __restrict__ W2c,
                       unsigned short* __restrict__ w1p, unsigned short* __restrict__ w2t) {
  __shared__ float row[7744];
  int bi = blockIdx.x, t = threadIdx.x;
  if (bi >= 384) {
    int head = bi - 384;
    const float* W2 = head == 0 ? W2a : (head == 1 ? W2b : W2c);
    int od = head == 0 ? 22 : 21;
    #pragma unroll
    for (int it = 0; it < 16; ++it) {
      int e = it * 256 + t;
      int n = e >> 7, k = e & 127;
      float v = (n < od) ? W2[n * 128 + k] : 0.0f;
      w2t[head * 4096 + e] = f2hbits(v);
    }
    return;
  }
  int head = bi >> 7, j = bi & 127;
  const float* W1; int rr, base;
  if (head == 0)      { W1 = W1a; rr = 9;   base = 0; }
  else if (head == 1) { W1 = W1b; rr = 49;  base = 147456; }
  else                { W1 = W1c; rr = 121; base = 950272; }
  int fin = rr * 64;
  for (int idx = t; idx < fin; idx += 256) row[idx] = W1[j * fin + idx];
  __syncthreads();
  int swz = (j & 7) << 4;
  for (int idx = t; idx < fin; idx += 256) {
    int c = idx & 63, p = idx >> 6;
    int byteoff = base + p * 16384 + ((j * 128 + c * 2) ^ swz);
    w1p[byteoff >> 1] = f2hbits(row[c * rr + p]);
  }
}

// ---- bilinear entry: {corner byte-offset, half2(wx,wy)} ----
__device__ __forceinline__ int2 mk_entry(float tx, float ty,
                                         float DX, float BX, float DY, float BY) {
  float ix = tx * DX + BX;
  float iy = ty * DY + BY;
  int x0 = min(max((int)floorf(ix), 0), 118);
  int y0 = min(max((int)floorf(iy), 0), 118);
  float wx = ix - (float)x0;
  float wy = iy - (float)y0;
  return make_int2((y0 * 120 + x0) * 128, (int)hu(__floats2half2_rn(wx, wy)));
}

__device__ __forceinline__ unsigned lerp1(unsigned aa, unsigned bb, unsigned cc, unsigned dd,
                                          __half2 wx2, __half2 wy2) {
  __half2 a = uh(aa), b = uh(bb), c = uh(cc), d = uh(dd);
  __half2 t = __hfma2(wx2, __hsub2(b, a), a);
  __half2 u2 = __hfma2(wx2, __hsub2(d, c), c);
  return hu(__hfma2(wy2, __hsub2(u2, t), t));
}

// issue sample loads for one point: 2 units (boxes sg, sg+64) x 4 corners x 16B
__device__ __forceinline__ void issue_pt(const char* lds, int ebOff, const char* __restrict__ fmT,
                                         int sg, int scg8, uint4 cs[2][4],
                                         __half2* wx2v, __half2* wy2v) {
  #pragma unroll
  for (int u = 0; u < 2; ++u) {
    int2 e = *(const int2*)(lds + ebOff + (sg + u * 64) * 8);
    __half2 wh = uh((unsigned)e.y);
    wx2v[u] = __half2half2(__low2half(wh));
    wy2v[u] = __half2half2(__high2half(wh));
    const char* src = fmT + e.x + scg8 * 16;
    cs[u][0] = *(const uint4*)(src);
    cs[u][1] = *(const uint4*)(src + 128);
    cs[u][2] = *(const uint4*)(src + 15360);
    cs[u][3] = *(const uint4*)(src + 15488);
  }
}

// ---- fused ROI-sample + layer-1 GEMM, 128-box tiles, T14 pipeline ----
// LDS: A [0,16K) ; B[2] [16K,48K) ; ebuf[2] [48K, 48K+2K)  (R7 structure, clean regs)
__global__ __launch_bounds__(512, 4) void k_main3(
    const char* __restrict__ fmT,
    const float* __restrict__ boxes,
    const char* __restrict__ w1p,
    unsigned short* __restrict__ pbuf)
{
  __shared__ __align__(16) char lds[51200];
  int bi = blockIdx.x;
  int head, tile, split;
  if (bi < 512)      { head = 2; tile = bi >> 3;  split = bi & 7; }        // 8 splits
  else if (bi < 704) { int b2 = bi - 512; head = 1; tile = b2 / 3; split = b2 - tile * 3; }
  else               { head = 0; tile = bi - 704; split = 0; }

  int psta, pcnt, w1base, R, rm; float invd;
  if (head == 2)      { psta = split ? 15 * split + 1 : 0; pcnt = split ? 15 : 16;
                        w1base = 950272; R = 11; rm = 5958;  invd = 0.1f; }
  else if (head == 1) { psta = split ? 16 * split + 1 : 0; pcnt = split ? 16 : 17;
                        w1base = 147456; R = 7;  rm = 9363;  invd = 0.166666667f; }
  else                { psta = 0; pcnt = 9; w1base = 0; R = 3; rm = 21846; invd = 0.5f; }

  int tid = threadIdx.x;
  int w = tid >> 6, lane = tid & 63;
  int l15 = lane & 15, kgrp = lane >> 4;
  int wm = w & 1, wc = w >> 1;          // wave tile: 64 boxes x 32 cols
  int sg = tid >> 3, scg8 = tid & 7;    // sampler: boxes sg, sg+64; 8-ch group
  int boxbase = tile * 128;

  // box params for entry compute (tid<128 owns box=tid)
  float DX = 0.f, BX = 0.f, DY = 0.f, BY = 0.f;
  if (tid < 128) {
    float4 bx = ((const float4*)boxes)[boxbase + tid];
    const float sc2 = 119.0f / 960.0f;
    DX = (bx.z - bx.x) * sc2; BX = bx.x * sc2;
    DY = (bx.w - bx.y) * sc2; BY = bx.y * sc2;
  }

  f4v acc[4][2];
  #pragma unroll
  for (int m = 0; m < 4; ++m)
    #pragma unroll
    for (int n = 0; n < 2; ++n) acc[m][n] = (f4v){0.f, 0.f, 0.f, 0.f};

  const char* w1g = w1p + w1base;
  uint4 cs[2][4];
  __half2 wx2v[2], wy2v[2];

  // ---- prologue: entries(0)->ebuf[0], entries(1)->ebuf[1]; GLD B(0) ----
  if (tid < 128) {
    #pragma unroll
    for (int q = 0; q < 2; ++q) {
      int p = psta + q;
      int py = (p * rm) >> 16, px = p - py * R;
      *(int2*)(lds + 49152 + q * 1024 + tid * 8) =
          mk_entry((float)px * invd, (float)py * invd, DX, BX, DY, BY);
    }
  }
  {
    const char* s0 = w1g + psta * 16384 + w * 2048 + lane * 16;
    char* d0 = lds + 16384 + w * 2048;
    GLD(s0, d0); GLD(s0 + 1024, d0 + 1024);
  }
  __syncthreads();
  issue_pt(lds, 49152, fmT, sg, scg8, cs, wx2v, wy2v);   // corners(0)

  for (int t = 0; t < pcnt; ++t) {
    int cur = t & 1, nxt = cur ^ 1;
    bool more = (t + 1) < pcnt;

    // ---- phase 1: lerp samples(t) -> A; compute entries(t+2) into regs ----
    #pragma unroll
    for (int u = 0; u < 2; ++u) {
      int sbox = sg + u * 64;
      uint4 r;
      r.x = lerp1(cs[u][0].x, cs[u][1].x, cs[u][2].x, cs[u][3].x, wx2v[u], wy2v[u]);
      r.y = lerp1(cs[u][0].y, cs[u][1].y, cs[u][2].y, cs[u][3].y, wx2v[u], wy2v[u]);
      r.z = lerp1(cs[u][0].z, cs[u][1].z, cs[u][2].z, cs[u][3].z, wx2v[u], wy2v[u]);
      r.w = lerp1(cs[u][0].w, cs[u][1].w, cs[u][2].w, cs[u][3].w, wx2v[u], wy2v[u]);
      *(uint4*)(lds + ((sbox * 128 + scg8 * 16) ^ ((sbox & 7) << 4))) = r;
    }
    int2 ne;
    if (tid < 128) {
      int p = psta + min(t + 2, pcnt - 1);
      int py = (p * rm) >> 16, px = p - py * R;
      ne = mk_entry((float)px * invd, (float)py * invd, DX, BX, DY, BY);
    }
    __syncthreads();   // bar1: A(t) visible

    // ---- phase 2: entries ds_write, GLD B(t+1), issue corners(t+1), MFMA(t) ----
    if (tid < 128) *(int2*)(lds + 49152 + cur * 1024 + tid * 8) = ne;
    if (more) {
      const char* s0 = w1g + (psta + t + 1) * 16384 + w * 2048 + lane * 16;
      char* d0 = lds + 16384 + nxt * 16384 + w * 2048;
      GLD(s0, d0); GLD(s0 + 1024, d0 + 1024);
      issue_pt(lds, 49152 + nxt * 1024, fmT, sg, scg8, cs, wx2v, wy2v);
    }
    {
      const char* bb = lds + 16384 + cur * 16384;
      #pragma unroll
      for (int ks = 0; ks < 2; ++ks) {
        int n0 = wc * 32 + l15, n1 = n0 + 16;
        h8v bf0 = *(const h8v*)(bb + ((n0 * 128 + ks * 64 + kgrp * 16) ^ ((n0 & 7) << 4)));
        h8v bf1 = *(const h8v*)(bb + ((n1 * 128 + ks * 64 + kgrp * 16) ^ ((n1 & 7) << 4)));
        #pragma unroll
        for (int m = 0; m < 4; ++m) {
          int rrow = wm * 64 + m * 16 + l15;
          h8v af = *(const h8v*)(lds + ((rrow * 128 + ks * 64 + kgrp * 16) ^ ((rrow & 7) << 4)));
          acc[m][0] = __builtin_amdgcn_mfma_f32_16x16x32_f16(af, bf0, acc[m][0], 0, 0, 0);
          acc[m][1] = __builtin_amdgcn_mfma_f32_16x16x32_f16(af, bf1, acc[m][1], 0, 0, 0);
        }
      }
    }
    __syncthreads();   // bar2: drains prefetches that flew during MFMA
  }

  // ---- epilogue: f16 partial -> pbuf[bi] ----
  unsigned short* pdst = pbuf + (size_t)bi * 16384;
  #pragma unroll
  for (int m = 0; m < 4; ++m)
    #pragma unroll
    for (int n = 0; n < 2; ++n)
      #pragma unroll
      for (int e = 0; e < 4; ++e) {
        int boxl = wm * 64 + m * 16 + kgrp * 4 + e;
        int cnl = wc * 32 + n * 16 + l15;
        pdst[boxl * 128 + cnl] = f2hbits(acc[m][n][e]);
      }
}

// ---- combine partials, bias+relu, layer-2 MFMA, write out (+g cols) ----
__global__ __launch_bounds__(256) void k_combine(
    const unsigned short* __restrict__ pbuf,
    const unsigned short* __restrict__ w2t,
    const float* __restrict__ gf,
    const float* __restrict__ Wg, const float* __restrict__ bg,
    const float* __restrict__ b1a, const float* __restrict__ b1b, const float* __restrict__ b1c,
    const float* __restrict__ b2a, const float* __restrict__ b2b, const float* __restrict__ b2c,
    const float* __restrict__ scale_w,
    float* __restrict__ out)
{
  __shared__ __align__(16) char lds[8192 + 256];
  float* gv = (float*)(lds + 8192);
  int b = blockIdx.x, tid = threadIdx.x;
  int tile = b >> 2, rowoff = (b & 3) * 32;
  int boxbase = b * 32;
  int w = tid >> 6, lane = tid & 63, l15 = lane & 15, kgrp = lane >> 4;

  if (tid < 16) {
    float s = bg[tid];
    for (int c = 0; c < 64; ++c) s += gf[c] * (1.0f / 14400.0f) * Wg[tid * 64 + c];
    gv[tid] = s;
  }

  int row = tid >> 3, col0 = (tid & 7) * 16;
  const float* b1s[3] = {b1a, b1b, b1c};
  const float* b2s[3] = {b2a, b2b, b2c};

  #pragma unroll
  for (int h = 0; h < 3; ++h) {
    int S, pb, colbase, odh;
    if (h == 0)      { S = 1; pb = 704 + tile;     colbase = 0;  odh = 22; }
    else if (h == 1) { S = 3; pb = 512 + tile * 3; colbase = 22; odh = 21; }
    else             { S = 8; pb = tile * 8;       colbase = 43; odh = 5; }

    float f[16];
    #pragma unroll
    for (int j = 0; j < 16; ++j) f[j] = 0.f;
    #pragma unroll
    for (int s = 0; s < 8; ++s) {
      if (s < S) {
        const unsigned short* src = pbuf + (size_t)(pb + s) * 16384 + (rowoff + row) * 128 + col0;
        uint4 v0 = *(const uint4*)(src);
        uint4 v1 = *(const uint4*)(src + 8);
        unsigned int uu[8] = {v0.x, v0.y, v0.z, v0.w, v1.x, v1.y, v1.z, v1.w};
        #pragma unroll
        for (int k = 0; k < 8; ++k) {
          __half2 hv = uh(uu[k]);
          f[k * 2]     += __low2float(hv);
          f[k * 2 + 1] += __high2float(hv);
        }
      }
    }
    unsigned int pk[8];
    #pragma unroll
    for (int k = 0; k < 8; ++k) {
      float a  = fmaxf(f[2 * k]     + b1s[h][col0 + 2 * k],     0.f);
      float c2 = fmaxf(f[2 * k + 1] + b1s[h][col0 + 2 * k + 1], 0.f);
      pk[k] = hu(__floats2half2_rn(a, c2));
    }
    int swz = (row & 15) << 4;
    int a0 = (row * 256 + col0 * 2) ^ swz;
    int a1 = (row * 256 + col0 * 2 + 16) ^ swz;
    *(uint4*)(lds + a0) = make_uint4(pk[0], pk[1], pk[2], pk[3]);
    *(uint4*)(lds + a1) = make_uint4(pk[4], pk[5], pk[6], pk[7]);
    __syncthreads();

    {
      int m = w & 1, n2 = w >> 1;
      f4v a2 = (f4v){0.f, 0.f, 0.f, 0.f};
      int hrow = m * 16 + l15, drow = n2 * 16 + l15;
      #pragma unroll
      for (int ks = 0; ks < 4; ++ks) {
        h8v ha = *(const h8v*)(lds + ((hrow * 256 + ks * 64 + kgrp * 16) ^ ((hrow & 15) << 4)));
        h8v wb = *(const h8v*)((const char*)w2t + h * 8192 + drow * 256 + ks * 64 + kgrp * 16);
        a2 = __builtin_amdgcn_mfma_f32_16x16x32_f16(ha, wb, a2, 0, 0, 0);
      }
      if (drow < odh) {
        float scv = scale_w[h];
        float b2v = b2s[h][drow];
        #pragma unroll
        for (int e = 0; e < 4; ++e) {
          int box = boxbase + m * 16 + kgrp * 4 + e;
          out[box * 64 + colbase + drow] = fmaxf(a2[e] + b2v, 0.f) * scv;
        }
      }
    }
    __syncthreads();
  }

  {
    int i0 = tid * 2;
    #pragma unroll
    for (int j2 = 0; j2 < 2; ++j2) {
      int idx = i0 + j2;
      out[(boxbase + (idx >> 4)) * 64 + 48 + (idx & 15)] = gv[idx & 15];
    }
  }
}

extern "C" void kernel_launch(void* const* d_in, const int* in_sizes, int n_in,
                              void* d_out, int out_size, void* d_ws, size_t ws_size,
                              hipStream_t stream) {
  const float* fm      = (const float*)d_in[0];
  const float* boxes   = (const float*)d_in[1];
  const float* W1a     = (const float*)d_in[2];
  const float* b1a     = (const float*)d_in[3];
  const float* W2a     = (const float*)d_in[4];
  const float* b2a     = (const float*)d_in[5];
  const float* W1b     = (const float*)d_in[6];
  const float* b1b     = (const float*)d_in[7];
  const float* W2b     = (const float*)d_in[8];
  const float* b2b     = (const float*)d_in[9];
  const float* W1c     = (const float*)d_in[10];
  const float* b1c     = (const float*)d_in[11];
  const float* W2c     = (const float*)d_in[12];
  const float* b2c     = (const float*)d_in[13];
  const float* scale_w = (const float*)d_in[14];
  const float* Wg      = (const float*)d_in[15];
  const float* bg      = (const float*)d_in[16];

  char* ws = (char*)d_ws;
  unsigned int* fmT32 = (unsigned int*)(ws + FMT_OFF);
  float* gf           = (float*)(ws + GF_OFF);
  unsigned short* w1p = (unsigned short*)(ws + W1P_OFF);
  unsigned short* w2t = (unsigned short*)(ws + W2T_OFF);
  unsigned short* pbuf= (unsigned short*)(ws + PBUF_OFF);
  float* out          = (float*)d_out;

  hipMemsetAsync(gf, 0, 256, stream);
  k_transpose<<<225, 256, 0, stream>>>(fm, fmT32, gf);
  k_w1w2<<<387, 256, 0, stream>>>(W1a, W1b, W1c, W2a, W2b, W2c, w1p, w2t);
  k_main3<<<768, 512, 0, stream>>>((const char*)ws + FMT_OFF, boxes,
                                   (const char*)ws + W1P_OFF, pbuf);
  k_combine<<<256, 256, 0, stream>>>(pbuf, w2t, gf, Wg, bg,
                                     b1a, b1b, b1c, b2a, b2b, b2c, scale_w, out);
}